// Round 6
// baseline (83.151 us; speedup 1.0000x reference)
//
#include <hip/hip_runtime.h>

#define IMG_H 2048
#define IMG_W 2048
#define RSTRIPE 8
#define NSTRIPES 256 // covers rows 1..2046
#define MAXBLOCKS 1024
#define MAGIC 0x5ca1ab1eu

typedef unsigned long long ull;

__device__ __forceinline__ unsigned interior_mask(int lane) {
    unsigned m = 0xffffffffu;
    if (lane == 0)  m &= ~1u;
    if (lane == 63) m &= 0x7fffffffu;
    return m;
}

struct RowCtx {
    unsigned b1, b2, b4, b8, b16, lowrun, a_static;
    ull B1, B2, B4, B8, B16, B32;
};

// ps-independent per-row precompute (shared between speculative chains)
__device__ __forceinline__ RowCtx make_ctx(unsigned cs, ull cs_lsb,
                                           unsigned ns, ull ns_lsb, ull ns_msb,
                                           unsigned wk, unsigned interior, int lane) {
    RowCtx c;
    c.b1 = wk & interior;
    unsigned rcs = (cs >> 1) | (((unsigned)((cs_lsb >> 1 >> lane) & 1ull)) << 31);
    unsigned rns = (ns >> 1) | (((unsigned)((ns_lsb >> 1 >> lane) & 1ull)) << 31);
    unsigned lns = (ns << 1) | ((unsigned)(((ns_msb << 1) >> lane) & 1ull));
    c.a_static = cs | (c.b1 & (rcs | lns | ns | rns));
    c.b2  = c.b1 & (c.b1 << 1);
    c.b4  = c.b2 & (c.b2 << 2);
    c.b8  = c.b4 & (c.b4 << 4);
    c.b16 = c.b8 & (c.b8 << 8);
    c.lowrun = c.b1 & (c.b1 ^ (c.b1 + 1u));   // low all-ones run of b1
    c.B1  = __ballot(c.b1 == 0xffffffffu);    // word fully propagates
    c.B2  = c.B1  & (c.B1  << 1);
    c.B4  = c.B2  & (c.B2  << 2);
    c.B8  = c.B4  & (c.B4  << 4);
    c.B16 = c.B8  & (c.B8  << 8);
    c.B32 = c.B16 & (c.B16 << 16);
    return c;
}

// one row of the recurrence: x[j] = a[j] | (b[j] & x[j-1]) closure, bit-parallel
__device__ __forceinline__ unsigned rowstep(unsigned ps, const RowCtx& c, int lane) {
    ull ps_msb = __ballot(ps >> 31);
    ull ps_lsb = __ballot(ps & 1u);
    unsigned lps = (ps << 1) | ((unsigned)(((ps_msb << 1) >> lane) & 1ull));
    unsigned rps = (ps >> 1) | (((unsigned)((ps_lsb >> 1 >> lane) & 1ull)) << 31);
    unsigned x = c.a_static | (c.b1 & (lps | ps | rps));
    x |= c.b1  & (x << 1);
    x |= c.b2  & (x << 2);
    x |= c.b4  & (x << 4);
    x |= c.b8  & (x << 8);
    x |= c.b16 & (x << 16);
    ull X = __ballot(x >> 31);
    X |= c.B1  & (X << 1);
    X |= c.B2  & (X << 2);
    X |= c.B4  & (X << 4);
    X |= c.B8  & (X << 8);
    X |= c.B16 & (X << 16);
    X |= c.B32 & (X << 32);
    unsigned carry = (unsigned)(((X << 1) >> lane) & 1ull);
    x |= carry ? c.lowrun : 0u;
    return x;
}

// classify one row: lane l produces word l (cols 32l..32l+31) of S and W
__device__ __forceinline__ void binrow(const float* __restrict__ img, int r, int lane,
                                       float high, float low,
                                       unsigned* sOut, unsigned* wOut) {
    const float4* p = (const float4*)(img + r * IMG_W + lane * 32);
    unsigned sb = 0, tb = 0;
#pragma unroll
    for (int i = 0; i < 8; ++i) {
        float4 v = p[i];
        sb |= (v.x > high ? 1u : 0u) << (4 * i);
        sb |= (v.y > high ? 1u : 0u) << (4 * i + 1);
        sb |= (v.z > high ? 1u : 0u) << (4 * i + 2);
        sb |= (v.w > high ? 1u : 0u) << (4 * i + 3);
        tb |= (v.x >= low ? 1u : 0u) << (4 * i);
        tb |= (v.y >= low ? 1u : 0u) << (4 * i + 1);
        tb |= (v.z >= low ? 1u : 0u) << (4 * i + 2);
        tb |= (v.w >= low ? 1u : 0u) << (4 * i + 3);
    }
    *sOut = sb;
    *wOut = tb & ~sb;   // weak = (x>=low) && !(x>high)
}

// ---------------- Phase 1: per-block max partials (plain stores) ------------
__global__ __launch_bounds__(256) void max_part_kernel(const float4* __restrict__ in,
                                                       float* __restrict__ partial) {
    __shared__ float sm[4];
    int base = blockIdx.x * 1024 + threadIdx.x;   // 1024 float4 per block
    float m = 0.0f;
#pragma unroll
    for (int i = 0; i < 4; ++i) {
        float4 v = in[base + i * 256];
        m = fmaxf(fmaxf(m, v.x), fmaxf(v.y, fmaxf(v.z, v.w)));
    }
#pragma unroll
    for (int off = 32; off > 0; off >>= 1)
        m = fmaxf(m, __shfl_down(m, off, 64));
    if ((threadIdx.x & 63) == 0) sm[threadIdx.x >> 6] = m;
    __syncthreads();
    if (threadIdx.x == 0)
        partial[blockIdx.x] = fmaxf(fmaxf(sm[0], sm[1]), fmaxf(sm[2], sm[3]));
}

// ---------------- Phase 2: everything else, one block per stripe ------------
// Block s: reduce partials -> maxv; binarize halo rows [start-1, start+8] into
// LDS; wave 0 runs dual-bound speculative scan (exact from first agreeing row);
// rare unconverged prefix fixed via decoupled lookback on done[s-1]; all waves
// expand the stripe's rows to d_out. Rows 0/2047 expanded by blocks 0/255.
__global__ __launch_bounds__(256) void mega_kernel(const float* __restrict__ img,
                                                   const float* __restrict__ partial,
                                                   float* __restrict__ out,
                                                   unsigned* __restrict__ Nlast,  // [256][64]
                                                   unsigned* __restrict__ done) { // [256]
    __shared__ unsigned ldsS[10][64], ldsW[10][64], ldsX[RSTRIPE][64];
    __shared__ float sm[4];
    const int t = threadIdx.x, wave = t >> 6, lane = t & 63;
    const int s = blockIdx.x;
    const int start = 1 + RSTRIPE * s;
    const int nown = min(start + RSTRIPE, 2047) - start;  // 8 (6 for s=255)

    // ---- global max from 1024 partials (every block does the full reduce) ----
    float m = fmaxf(fmaxf(partial[t], partial[t + 256]),
                    fmaxf(partial[t + 512], partial[t + 768]));
#pragma unroll
    for (int off = 32; off > 0; off >>= 1)
        m = fmaxf(m, __shfl_down(m, off, 64));
    if (lane == 0) sm[wave] = m;
    __syncthreads();
    const float maxv = fmaxf(fmaxf(sm[0], sm[1]), fmaxf(sm[2], sm[3]));
    const float high = maxv * 0.15f;
    const float low  = high * 0.05f;

    // ---- binarize 10 halo rows into LDS (4 waves split the rows) ----
    for (int u = wave; u < 10; u += 4) {
        int r = min(start - 1 + u, 2047);
        unsigned sb, wb;
        binrow(img, r, lane, high, low, &sb, &wb);
        ldsS[u][lane] = sb;
        ldsW[u][lane] = wb;
    }
    __syncthreads();

    // ---- wave 0: dual-bound spec + rare lookback fix ----
    if (wave == 0) {
        const unsigned interior = interior_mask(lane);
        unsigned pcs = ldsS[0][lane], pw = ldsW[0][lane];
        unsigned psl = pcs;
        unsigned psu = (s == 0) ? pcs : (pcs | (pw & interior));  // row 0 exact
        unsigned cs = ldsS[1][lane];
        ull cs_lsb = __ballot(cs & 1u);
        int conv_u = nown;            // first exact local row; sentinel = nown
        bool converged = false;
#pragma unroll
        for (int u = 0; u < RSTRIPE; ++u) {
            if (u < nown) {                       // uniform guard
                unsigned ns = ldsS[u + 2][lane];
                unsigned wk = ldsW[u + 1][lane];
                ull ns_lsb = __ballot(ns & 1u);
                ull ns_msb = __ballot(ns >> 31);
                RowCtx c = make_ctx(cs, cs_lsb, ns, ns_lsb, ns_msb, wk, interior, lane);
                unsigned xu = rowstep(psu, c, lane);
                unsigned xl;
                if (!converged) {                 // uniform
                    xl = rowstep(psl, c, lane);
                    if (__ballot(xl != xu) == 0ull) { converged = true; conv_u = u; }
                } else {
                    xl = xu;
                }
                ldsX[u][lane] = xu;
                psl = xl;
                psu = xu;
                cs = ns;
                cs_lsb = ns_lsb;
            }
        }
        if (s > 0 && conv_u > 0) {
            // need the true incoming state: wait for stripe s-1 (rare path)
            if (lane == 0) {
                while (atomicOr(&done[s - 1], 0u) != MAGIC) {}
            }
            __threadfence();                      // acquire: see s-1's Nlast
            unsigned ps = Nlast[(s - 1) * 64 + lane];
            unsigned cs2 = ldsS[1][lane];
            ull cs2_lsb = __ballot(cs2 & 1u);
            for (int u = 0; u < conv_u; ++u) {    // conv_u uniform
                unsigned ns = ldsS[u + 2][lane];
                unsigned wk = ldsW[u + 1][lane];
                ull ns_lsb = __ballot(ns & 1u);
                ull ns_msb = __ballot(ns >> 31);
                RowCtx c = make_ctx(cs2, cs2_lsb, ns, ns_lsb, ns_msb, wk, interior, lane);
                unsigned x = rowstep(ps, c, lane);
                ldsX[u][lane] = x;
                ps = x;
                cs2 = ns;
                cs2_lsb = ns_lsb;
            }
        }
        if (s < NSTRIPES - 1) {                   // publish final last row
            Nlast[s * 64 + lane] = ldsX[RSTRIPE - 1][lane];
            __threadfence();                      // release
            if (lane == 0) atomicExch(&done[s], MAGIC);
        }
    }
    __syncthreads();

    // ---- expand stripe rows to fp32 output (4 waves split rows) ----
    for (int u = wave; u < nown; u += 4) {
        int r = start + u;
        unsigned x = ldsX[u][lane];
        unsigned w = ldsW[u + 1][lane];
        float4* po = (float4*)(out + r * IMG_W + lane * 32);
#pragma unroll
        for (int i = 0; i < 8; ++i) {
            float4 o;
            float* f = (float*)&o;
#pragma unroll
            for (int k2 = 0; k2 < 4; ++k2) {
                int k = 4 * i + k2;
                bool sn = (x >> k) & 1u;
                bool wb = (w >> k) & 1u;
                bool ec = (lane == 0 && k == 0) || (lane == 63 && k == 31);
                f[k2] = sn ? 255.0f : ((wb && ec) ? 25.0f : 0.0f);
            }
            po[i] = o;
        }
    }
    // edge rows pass through the classification directly
    if ((s == 0 && wave == 1) || (s == NSTRIPES - 1 && wave == 2)) {
        int u = (s == 0) ? 0 : 7;                 // lds row for global row 0 / 2047
        int r = (s == 0) ? 0 : 2047;
        unsigned sw = ldsS[u][lane];
        unsigned ww = ldsW[u][lane];
        float4* po = (float4*)(out + r * IMG_W + lane * 32);
#pragma unroll
        for (int i = 0; i < 8; ++i) {
            float4 o;
            float* f = (float*)&o;
#pragma unroll
            for (int k2 = 0; k2 < 4; ++k2) {
                int k = 4 * i + k2;
                bool sn = (sw >> k) & 1u;
                bool wb = (ww >> k) & 1u;
                f[k2] = sn ? 255.0f : (wb ? 25.0f : 0.0f);
            }
            po[i] = o;
        }
    }
}

extern "C" void kernel_launch(void* const* d_in, const int* in_sizes, int n_in,
                              void* d_out, int out_size, void* d_ws, size_t ws_size,
                              hipStream_t stream) {
    const float* img = (const float*)d_in[0];
    char* ws = (char*)d_ws;
    float* partial = (float*)(ws);               // 4 KiB (1024 floats)
    unsigned* done  = (unsigned*)(ws + 8192);    // 1 KiB (poison 0xAA != MAGIC)
    unsigned* Nlast = (unsigned*)(ws + 16384);   // 64 KiB (256 x 64 words)

    max_part_kernel<<<MAXBLOCKS, 256, 0, stream>>>((const float4*)img, partial);
    mega_kernel<<<NSTRIPES, 256, 0, stream>>>(img, partial, (float*)d_out, Nlast, done);
}